// Round 16
// baseline (498.137 us; speedup 1.0000x reference)
//
#include <hip/hip_runtime.h>
#include <hip/hip_bf16.h>
#include <math.h>

using bf16 = __hip_bfloat16;
typedef __attribute__((ext_vector_type(8))) short bfx8;   // 8 x bf16 MFMA frag
typedef __attribute__((ext_vector_type(4))) float fx4;    // MFMA accum

#define DI __device__ __forceinline__

#define B_  4
#define L_  2048
#define D_  1024
#define M_  256
#define N_  8192            /* B*L tokens */
#define H_  256
#define CCH 32
#define TCH 64

// counted-vmcnt pipeline sync (T4): wait only for the OLDER stage's loads.
#define PIPE_SYNC(NSTR) asm volatile("s_waitcnt vmcnt(" NSTR ")\n\ts_barrier" ::: "memory")
#define PIPE_BAR()      asm volatile("s_barrier" ::: "memory")

DI float us2f(unsigned short u){ unsigned int i=((unsigned int)u)<<16; float f; __builtin_memcpy(&f,&i,4); return f; }
DI unsigned short f2bu(float f){ bf16 h=__float2bfloat16(f); unsigned short u; __builtin_memcpy(&u,&h,2); return u; }
DI float b2f(bf16 v){ return __bfloat162float(v); }
DI float siluf(float x){ return x/(1.f+expf(-x)); }
DI float geluf(float x){ return 0.5f*x*(1.f+erff(x*0.70710678118654752f)); }

DI void gload_lds16(const bf16* g, bf16* l){
  __builtin_amdgcn_global_load_lds((const __attribute__((address_space(1))) void*)g,
                                   (__attribute__((address_space(3))) void*)l, 16, 0, 0);
}

// ---- merged: weight prep (blocks 0..1023) + router-algebra stage1 (blocks 1024..1183) ----
__global__ __launch_bounds__(256) void k_prep1(const float* __restrict__ pw_w, const float* __restrict__ val_w,
    const float* __restrict__ gate_w, const float* __restrict__ exp_w, const float* __restrict__ out_w,
    const float* __restrict__ down_w, const float* __restrict__ up_w, const float* __restrict__ rw,
    bf16* pwh, bf16* pwl, bf16* valh, bf16* vall, bf16* gatebf, bf16* expb, bf16* outb, bf16* downb, bf16* upb,
    float* __restrict__ part)
{
  if (blockIdx.x < 1024){
    for (int i = blockIdx.x*256 + threadIdx.x; i < 2097152; i += 1024*256){
      const float* src; bf16* dsth; bf16* dstl = nullptr; int off;
      if (i < 262144)      { src=pw_w;   dsth=pwh;    dstl=pwl;  off=i; }
      else if (i < 327680) { src=val_w;  dsth=valh;   dstl=vall; off=i-262144; }
      else if (i < 655360) { src=gate_w; dsth=gatebf;            off=i-327680; }
      else if (i < 1703936){ src=exp_w;  dsth=expb;              off=i-655360; }
      else if (i < 1966080){ src=out_w;  dsth=outb;              off=i-1703936; }
      else if (i < 2031616){ src=down_w; dsth=downb;             off=i-1966080; }
      else                 { src=up_w;   dsth=upb;               off=i-2031616; }
      const float4 f = ((const float4*)src)[off];
      ushort4 h; h.x=f2bu(f.x); h.y=f2bu(f.y); h.z=f2bu(f.z); h.w=f2bu(f.w);
      ((ushort4*)dsth)[off] = h;
      if (dstl){
        ushort4 l;
        l.x=f2bu(f.x-us2f(h.x)); l.y=f2bu(f.y-us2f(h.y));
        l.z=f2bu(f.z-us2f(h.z)); l.w=f2bu(f.w-us2f(h.w));
        ((ushort4*)dstl)[off] = l;
      }
    }
  } else {
    const int bid = blockIdx.x - 1024;
    const int oc = bid/20, kb = bid - oc*20;
    const int ek = kb*256 + threadIdx.x;          // 0..5119
    const int e = ek/1280, k = ek - e*1280;
    const float* rwe = rw + e*1024 + oc*128;
    const float* g   = gate_w + (size_t)(oc*128)*1280 + k;
    float acc = 0.f;
    #pragma unroll 8
    for (int o=0;o<128;o++) acc = fmaf(rwe[o], g[(size_t)o*1280], acc);
    part[oc*5120 + ek] = acc;
  }
}

// ---- stage 2: R[e,k] = sum_oc part + rw[e,k] (k<1024); c0[e] = rw.gate_b + rb[e] ----
__global__ __launch_bounds__(256) void k_precomp2(const float* __restrict__ part, const float* __restrict__ rw,
                                                  const float* __restrict__ gb, const float* __restrict__ rb,
                                                  float* __restrict__ R, float* __restrict__ c0)
{
  const int ek = blockIdx.x*256 + threadIdx.x;
  if (ek < 5120){
    float s = 0.f;
    #pragma unroll
    for (int oc=0;oc<8;oc++) s += part[oc*5120 + ek];
    const int e = ek/1280, k = ek - e*1280;
    if (k < 1024) s += rw[e*1024 + k];
    R[ek] = s;
  } else if (ek < 5124){
    const int e = ek - 5120;
    float acc = rb[e];
    const float* rwe = rw + e*1024;
    #pragma unroll 8
    for (int o=0;o<1024;o++) acc = fmaf(rwe[o], gb[o], acc);
    c0[e] = acc;
  }
}

// ---------------- RMS norm (block = 1 token; in-place safe) ----------------
template<bool BF_OUT2>
__global__ __launch_bounds__(256) void k_rms(const float* inp, const float* __restrict__ w,
                                             float* outf, bf16* __restrict__ outbf)
{
  const int n = blockIdx.x, t = threadIdx.x;
  const float4 f = *((const float4*)inp + (size_t)n*(D_/4) + t);
  float s = f.x*f.x+f.y*f.y+f.z*f.z+f.w*f.w;
  #pragma unroll
  for (int off=32; off; off>>=1) s += __shfl_xor(s, off, 64);
  __shared__ float red[4];
  if ((t&63)==0) red[t>>6]=s;
  __syncthreads();
  const float inv = 1.f/sqrtf((red[0]+red[1]+red[2]+red[3])*(1.f/(float)D_)+1e-6f);
  const float4 wv = *((const float4*)w + t);
  float4 of;
  of.x = wv.x*f.x*inv; of.y = wv.y*f.y*inv; of.z = wv.z*f.z*inv; of.w = wv.w*f.w*inv;
  *((float4*)outf + (size_t)n*(D_/4) + t) = of;
  if constexpr (BF_OUT2){
    ushort4 ub; ub.x=f2bu(of.x); ub.y=f2bu(of.y); ub.z=f2bu(of.z); ub.w=f2bu(of.w);
    *((ushort4*)outbf + (size_t)n*(D_/4) + t) = ub;
  }
}

// ---------------- causal depthwise conv K=5; out split hi/lo ----------------
__global__ __launch_bounds__(256) void k_conv(const float* __restrict__ h0, const float* __restrict__ dww,
                                              const float* __restrict__ dwb,
                                              bf16* __restrict__ yhi, bf16* __restrict__ ylo)
{
  const int n = blockIdx.x, t = threadIdx.x;
  const int l = n & (L_-1);
  const int d0 = t*4;
  float a0=dwb[d0+0], a1=dwb[d0+1], a2=dwb[d0+2], a3=dwb[d0+3];
  #pragma unroll
  for (int k=0;k<5;k++){
    if (l-4+k < 0) continue;
    const float4 h4 = *(const float4*)&h0[(size_t)(n+k-4)*D_ + d0];
    a0 += h4.x*dww[(d0+0)*5+k];
    a1 += h4.y*dww[(d0+1)*5+k];
    a2 += h4.z*dww[(d0+2)*5+k];
    a3 += h4.w*dww[(d0+3)*5+k];
  }
  ushort4 hi, lo;
  hi.x=f2bu(a0); lo.x=f2bu(a0-us2f(hi.x));
  hi.y=f2bu(a1); lo.y=f2bu(a1-us2f(hi.y));
  hi.z=f2bu(a2); lo.z=f2bu(a2-us2f(hi.z));
  hi.w=f2bu(a3); lo.w=f2bu(a3-us2f(hi.w));
  *((ushort4*)yhi + (size_t)n*(D_/4) + t) = hi;
  *((ushort4*)ylo + (size_t)n*(D_/4) + t) = lo;
}

// ---------------- chunked scan (in-place over v; adds val bias) ----------------
__global__ __launch_bounds__(256) void k_scan1(float* vw, float* __restrict__ carry,
                                               const float* __restrict__ td, const float* __restrict__ vb)
{
  const int bc = blockIdx.x, m = threadIdx.x;
  const int b = bc>>5, c = bc&(CCH-1);
  const float decay = 0.9f/(1.f+expf(-td[m])) + 0.1f;
  const float bias = vb[m];
  float* wp = vw + ((size_t)b*L_ + c*TCH)*M_ + m;
  float a = 0.f;
  for (int i=0;i<TCH;i++){ a = a*decay + (wp[(size_t)i*M_] + bias); wp[(size_t)i*M_] = a; }
  carry[(size_t)bc*M_ + m] = a;
}

// scan3 with inline carry-prefix (replaces scan2): cin = Horner over raw chunk-ends, same fp order
__global__ __launch_bounds__(256) void k_scan3(const float* __restrict__ wv, const float* __restrict__ carry,
                                               const float* __restrict__ mem, const float* __restrict__ td,
                                               const float* __restrict__ tf,
                                               bf16* __restrict__ wvhi, bf16* __restrict__ wvlo,
                                               float* __restrict__ nextmem)
{
  const int bc = blockIdx.x, m = threadIdx.x;
  const int b = bc>>5, c = bc&(CCH-1);
  const float decay = 0.9f/(1.f+expf(-td[m])) + 0.1f;
  const float dT = powf(decay, (float)TCH);
  float cin = 0.f;
  for (int j=0;j<c;j++) cin = carry[((size_t)(b*CCH+j))*M_ + m] + dT*cin;
  const float memc = mem[b*M_+m] / (1.f+expf(-tf[m]));
  const float* wp = wv + ((size_t)b*L_ + c*TCH)*M_ + m;
  float p = 1.f;
  for (int i=0;i<TCH;i++){
    p *= decay;
    const float val = wp[(size_t)i*M_] + p*cin + memc;
    const int l = c*TCH+i;
    const size_t n = (size_t)b*L_ + l;
    const unsigned short h = f2bu(val);
    wvhi[n*M_ + m] = *(const bf16*)&h;
    const unsigned short lo = f2bu(val - us2f(h));
    wvlo[n*M_ + m] = *(const bf16*)&lo;
    if (l == L_-1) nextmem[b*M_+m] = val;
  }
}

// ---------------- precise router: logits = h1.R1^T + wv.R2^T + c0 ; top-2 softmax -> gates ----------------
__global__ __launch_bounds__(256) void k_rgemv(const bf16* __restrict__ h1hi, const bf16* __restrict__ h1lo,
                                               const bf16* __restrict__ wvhi, const bf16* __restrict__ wvlo,
                                               const float* __restrict__ R, const float* __restrict__ c0,
                                               float* __restrict__ gates)
{
  const int wave = threadIdx.x>>6, lane = threadIdx.x&63;
  const size_t n = (size_t)blockIdx.x*4 + wave;
  float p0=0,p1=0,p2=0,p3=0;
  const ushort4* hhi = (const ushort4*)(h1hi + n*D_);
  const ushort4* hlo = (const ushort4*)(h1lo + n*D_);
  #pragma unroll
  for (int c=0;c<4;c++){
    const int k4 = c*64 + lane;
    const ushort4 uh = hhi[k4], ul = hlo[k4];
    const float v0=us2f(uh.x)+us2f(ul.x), v1=us2f(uh.y)+us2f(ul.y);
    const float v2=us2f(uh.z)+us2f(ul.z), v3=us2f(uh.w)+us2f(ul.w);
    const float4 r0 = *(const float4*)&R[0*1280 + k4*4];
    const float4 r1 = *(const float4*)&R[1*1280 + k4*4];
    const float4 r2 = *(const float4*)&R[2*1280 + k4*4];
    const float4 r3 = *(const float4*)&R[3*1280 + k4*4];
    p0 += v0*r0.x+v1*r0.y+v2*r0.z+v3*r0.w;
    p1 += v0*r1.x+v1*r1.y+v2*r1.z+v3*r1.w;
    p2 += v0*r2.x+v1*r2.y+v2*r2.z+v3*r2.w;
    p3 += v0*r3.x+v1*r3.y+v2*r3.z+v3*r3.w;
  }
  {
    const ushort4 uh = ((const ushort4*)(wvhi + n*M_))[lane];
    const ushort4 ul = ((const ushort4*)(wvlo + n*M_))[lane];
    const float v0=us2f(uh.x)+us2f(ul.x), v1=us2f(uh.y)+us2f(ul.y);
    const float v2=us2f(uh.z)+us2f(ul.z), v3=us2f(uh.w)+us2f(ul.w);
    const float4 r0 = *(const float4*)&R[0*1280 + 1024 + lane*4];
    const float4 r1 = *(const float4*)&R[1*1280 + 1024 + lane*4];
    const float4 r2 = *(const float4*)&R[2*1280 + 1024 + lane*4];
    const float4 r3 = *(const float4*)&R[3*1280 + 1024 + lane*4];
    p0 += v0*r0.x+v1*r0.y+v2*r0.z+v3*r0.w;
    p1 += v0*r1.x+v1*r1.y+v2*r1.z+v3*r1.w;
    p2 += v0*r2.x+v1*r2.y+v2*r2.z+v3*r2.w;
    p3 += v0*r3.x+v1*r3.y+v2*r3.z+v3*r3.w;
  }
  #pragma unroll
  for (int off=32; off; off>>=1){
    p0 += __shfl_xor(p0, off, 64); p1 += __shfl_xor(p1, off, 64);
    p2 += __shfl_xor(p2, off, 64); p3 += __shfl_xor(p3, off, 64);
  }
  if (lane==0){
    float lg[4] = {p0+c0[0], p1+c0[1], p2+c0[2], p3+c0[3]};
    int i1=0; float m1=lg[0];
    #pragma unroll
    for (int e=1;e<4;e++) if (lg[e]>m1){ m1=lg[e]; i1=e; }
    int i2=-1; float m2=-1e30f;
    #pragma unroll
    for (int e=0;e<4;e++) if (e!=i1 && lg[e]>m2){ m2=lg[e]; i2=e; }
    const float ex = expf(m2-m1);
    const float w1 = 1.f/(1.f+ex), w2 = ex/(1.f+ex);
    float4 g; g.x=0; g.y=0; g.z=0; g.w=0;
    ((float*)&g)[i1]=w1; ((float*)&g)[i2]=w2;
    *(float4*)&gates[n*4] = g;
  }
}

// ---------------- MoE bookkeeping ----------------
__global__ __launch_bounds__(256) void k_count(const float* __restrict__ gates, int* __restrict__ cnt)
{
  const int n = blockIdx.x*256 + threadIdx.x;
  const float4 g = *(const float4*)&gates[(size_t)n*4];
  if (g.x>0.f) atomicAdd(&cnt[0],1);
  if (g.y>0.f) atomicAdd(&cnt[1],1);
  if (g.z>0.f) atomicAdd(&cnt[2],1);
  if (g.w>0.f) atomicAdd(&cnt[3],1);
}

DI void base_from_cnt(const int* cnt, int* basearr){
  int s = 0;
  #pragma unroll
  for (int e=0;e<4;e++){ basearr[e]=s; s += ((cnt[e]+127)>>7)<<7; }
  basearr[4] = s;
}

// wave-aggregated position assignment; base computed inline from cnt
__global__ __launch_bounds__(256) void k_assign(const float* __restrict__ gates, const int* __restrict__ cnt,
                                                int* __restrict__ cnt2, unsigned int* __restrict__ midx,
                                                float* __restrict__ mw)
{
  int cl[4] = {cnt[0],cnt[1],cnt[2],cnt[3]};
  int basearr[5]; base_from_cnt(cl, basearr);
  const int n = blockIdx.x*256 + threadIdx.x;
  const int lane = threadIdx.x & 63;
  const float4 g = *(const float4*)&gates[(size_t)n*4];
  const float ga[4] = {g.x,g.y,g.z,g.w};
  int ea=-1, ebx=-1; float wa=0.f, wb=0.f;
  #pragma unroll
  for (int e=0;e<4;e++){
    const float ge = ga[e];
    if (ge>0.f){ if (ea<0){ea=e;wa=ge;} else {ebx=e;wb=ge;} }
  }
  int s0e, s1e=-1; float s0w, s1w=0.f;
  if (ebx<0){ s0e=ea; s0w=wa; }
  else if (wa>=wb){ s0e=ea; s0w=wa; s1e=ebx; s1w=wb; }
  else            { s0e=ebx; s0w=wb; s1e=ea; s1w=wa; }

  #pragma unroll
  for (int e=0;e<4;e++){
    #pragma unroll
    for (int slot=0;slot<2;slot++){
      const bool want = (slot==0) ? (s0e==e) : (s1e==e);
      const unsigned long long mask = __ballot(want);
      if (mask == 0ull) continue;
      const int leader = __ffsll((long long)mask) - 1;
      int pos = 0;
      if (lane == leader) pos = atomicAdd(&cnt2[e], __popcll(mask));
      pos = __shfl(pos, leader, 64);
      if (want){
        const int rank = __popcll(mask & ((1ull<<lane)-1ull));
        const int idx = basearr[e] + pos + rank;
        midx[idx] = (unsigned)n | (slot ? 0x80000000u : 0u);
        mw[idx]   = slot ? s1w : s0w;
      }
    }
  }
}

// ---------------- sparse expert GEMM: TRI-BUFFER 1-barrier/step pipeline, setprio ----------------
// Per step: {vmcnt(4); s_barrier; stage(s+2 -> C); compute(b[s])}. Race-free because the
// stage target C was last computed at step s-1 (before this barrier), and vmcnt(4)+barrier
// guarantees every wave's stage(s) loads have landed before any wave computes step s.
__global__ __launch_bounds__(256) void k_expa(const bf16* __restrict__ A, const bf16* __restrict__ Wall,
                                              const float* __restrict__ eb,
                                              const unsigned int* __restrict__ midx, const float* __restrict__ mw,
                                              const int* __restrict__ cnt,
                                              bf16* __restrict__ S0, bf16* __restrict__ S1)
{
  __shared__ __align__(16) bf16 smem[3*8192];    // 48KB tri-buffer

  int cl[4] = {cnt[0],cnt[1],cnt[2],cnt[3]};
  int basearr[5]; base_from_cnt(cl, basearr);
  const int nrb = basearr[4]>>7;

  const int bid = blockIdx.x;
  const int id2 = (bid&7)*132 + (bid>>3);          // XCD swizzle
  const int rblk = id2>>3, bcol0 = (id2&7)<<7;
  if (rblk >= nrb) return;
  const int row0 = rblk<<7;
  int e=0;
  if (row0 >= basearr[1]) e=1;
  if (row0 >= basearr[2]) e=2;
  if (row0 >= basearr[3]) e=3;
  const int loc0 = row0 - basearr[e];
  const int cnte = cl[e];

  const int t = threadIdx.x, wave = t>>6, lane = t&63;
  const int wm = wave>>1, wn = wave&1;
  fx4 acc[4][4] = {};

  const int sr = t>>2;
  const int sc = ((t&3) ^ ((t>>3)&3))*8;
  const unsigned mr0 = midx[row0+sr], mr1 = midx[row0+64+sr];
  const int tok0 = min((int)(mr0 & 0x7FFFFFFFu), N_-1);
  const int tok1 = min((int)(mr1 & 0x7FFFFFFFu), N_-1);
  const bf16* gA0 = A + (size_t)tok0*D_ + sc;
  const bf16* gA1 = A + (size_t)tok1*D_ + sc;
  const bf16* gW0 = Wall + (size_t)e*D_*D_ + (size_t)(bcol0+sr)*D_ + sc;
  const bf16* gW1 = gW0 + (size_t)64*D_;

  const int koff = ((lane>>4) ^ ((lane>>1)&3))*8;
  const int aoff = (wm*64 + (lane&15))*32 + koff;
  const int boff = (wn*64 + (lane&15))*32 + koff;

  // static tri-buffer pointers
  bf16* const dA_0 = smem + wave*512;            bf16* const dW_0 = smem + 4096 + wave*512;
  bf16* const dA_1 = smem + 8192 + wave*512;     bf16* const dW_1 = smem + 8192 + 4096 + wave*512;
  bf16* const dA_2 = smem + 16384 + wave*512;    bf16* const dW_2 = smem + 16384 + 4096 + wave*512;
  const bf16* const Ash0 = smem;
  const bf16* const Ash1 = smem + 8192;
  const bf16* const Ash2 = smem + 16384;

  auto stage = [&](int kk, bf16* dA, bf16* dW){
    gload_lds16(gA0 + kk, dA);
    gload_lds16(gA1 + kk, dA + 2048);
    gload_lds16(gW0 + kk, dW);
    gload_lds16(gW1 + kk, dW + 2048);
  };
  auto compute = [&](const bf16* Ash){
    const bf16* Wsh = Ash + 4096;
    bfx8 ah[4], wh[4];
    #pragma unroll
    for (int i=0;i<4;i++){
      ah[i] = *(const bfx8*)&Ash[aoff + i*512];
      wh[i] = *(const bfx8*)&Wsh[boff + i*512];
    }
    __builtin_amdgcn_s_setprio(1);
    #pragma unroll
    for (int i=0;i<4;i++)
      #pragma unroll
      for (int j=0;j<4;j++)
        acc[i][j] = __builtin_amdgcn_mfma_f32_16x16x32_bf16(ah[i], wh[j], acc[i][j], 0,0,0);
    __builtin_amdgcn_s_setprio(0);
  };

  // prologue: steps 0,1 staged (8 loads in flight)
  stage(0,  dA_0, dW_0);
  stage(32, dA_1, dW_1);
  // steps 0..29, unrolled by 3 (all stages unconditional: last stage = step 31 at it=9)
  for (int it=0; it<10; ++it){
    const int kk = it*96;                        // 3 steps * 32
    PIPE_SYNC("4");  stage(kk+64,  dA_2, dW_2);  compute(Ash0);
    PIPE_SYNC("4");  stage(kk+96,  dA_0, dW_0);  compute(Ash1);
    PIPE_SYNC("4");  stage(kk+128, dA_1, dW_1);  compute(Ash2);
  }
  // epilogue: steps 30 (buf0), 31 (buf1)
  PIPE_SYNC("4");  compute(Ash0);
  PIPE_SYNC("0");  compute(Ash1);

  const int r0l = wm*64 + (lane>>4)*4;
  const int c0l = wn*64 + (lane&15);
  #pragma unroll
  for (int i=0;i<4;i++){
    #pragma unroll
    for (int r=0;r<4;r++){
      const int loc = loc0 + r0l + i*16 + r;
      if (loc >= cnte) continue;
      const int gr = row0 + r0l + i*16 + r;
      const unsigned mi = midx[gr];
      const int tok = (int)(mi & 0x7FFFFFFFu);
      const float w = mw[gr];
      bf16* Sd = (mi & 0x80000000u) ? S1 : S0;
      #pragma unroll
      for (int j=0;j<4;j++){
        const int col = bcol0 + c0l + j*16;
        const float v = acc[i][j][r] + eb[(e<<10)+col];
        Sd[(size_t)tok*D_ + col] = __float2bfloat16(w*siluf(v));
      }
    }
  }
}
// NOTE: the loop stages steps up to kk+128 = 9*96+128 = 992 = step 31 at it=9; steps 30/31
// land in buf0/buf1; max outstanding = 8 loads (2 stages) at any wait. Audited race-free.

// ---------------- combine: combbf = bf16(S0 + S1) ----------------
__global__ __launch_bounds__(256) void k_combine(const bf16* __restrict__ S0, const bf16* __restrict__ S1,
                                                 bf16* __restrict__ o, int n4)
{
  int i = blockIdx.x*256 + threadIdx.x;
  const int stride = gridDim.x*256;
  for (; i<n4; i+=stride){
    const ushort4 a = ((const ushort4*)S0)[i];
    const ushort4 b = ((const ushort4*)S1)[i];
    ushort4 c;
    c.x = f2bu(us2f(a.x)+us2f(b.x));
    c.y = f2bu(us2f(a.y)+us2f(b.y));
    c.z = f2bu(us2f(a.z)+us2f(b.z));
    c.w = f2bu(us2f(a.w)+us2f(b.w));
    ((ushort4*)o)[i] = c;
  }
}

// ---------------- MFMA GEMM (static dbuf, depth-2 counted-vmcnt pipeline) ----------------
enum GMode { MODE_PW=0, MODE_VAL, MODE_GATE, MODE_OUTW, MODE_DOWN, MODE_UP };

template<int MODE>
__global__ __launch_bounds__(256)
void k_gemm(const bf16* __restrict__ Ah, const bf16* __restrict__ Al, const int lda,
            const bf16* __restrict__ A2h,
            const bf16* __restrict__ Wh, const bf16* __restrict__ Wl, const int K,
            const float* __restrict__ bias,
            float* Cf, const int ldc,
            bf16* __restrict__ Cb1, bf16* __restrict__ Cb2, const int ldcb,
            const float* resf, const int ldres,
            const float* __restrict__ xin, const float* __restrict__ rs)
{
  constexpr bool SPLIT = (MODE==MODE_PW || MODE==MODE_VAL);   // 3-pass hi/lo precision
  constexpr bool DUAL  = (MODE==MODE_GATE);                   // K>1024 from wv segment
  constexpr int  BUFS  = SPLIT ? 16384 : 8192;
  constexpr int  KSTEPS = (MODE==MODE_VAL || MODE==MODE_UP) ? 8 : (MODE==MODE_GATE ? 40 : 32);
  constexpr int  PAIRS  = (KSTEPS-2)/2;
  __shared__ __align__(16) bf16 smem[2*BUFS];

  const int t = threadIdx.x, wave = t>>6, lane = t&63;
  const int bid = blockIdx.x;
  int brow, bcol, kz = 0;
  if constexpr (MODE==MODE_VAL){
    const int id2 = (bid&7)*64 + (bid>>3);
    const int ct = id2 & 7;
    bcol = (ct&1)<<7; kz = ct>>1; brow = (id2>>3)<<7;
  } else if constexpr (MODE==MODE_DOWN){
    const int id2 = (bid&7)*16 + (bid>>3);
    bcol = (id2&1)<<7; brow = (id2>>1)<<7;
  } else {
    const int id2 = (bid&7)*64 + (bid>>3);
    bcol = (id2&7)<<7; brow = (id2>>3)<<7;
  }
  const int wm = wave>>1, wn = wave&1;
  fx4 acc[4][4] = {};

  const int sr = t>>2;
  const int sc = ((t&3) ^ ((t>>3)&3))*8;
  const size_t rg = (size_t)(brow+sr);
  const bf16* gAh0 = Ah + rg*lda + sc;
  const bf16* gAh1 = gAh0 + (size_t)64*lda;
  const bf16* gAl0 = SPLIT ? Al + rg*lda + sc : nullptr;
  const bf16* gAl1 = SPLIT ? gAl0 + (size_t)64*lda : nullptr;
  const bf16* gWh0 = Wh + (size_t)(bcol+sr)*K + sc;
  const bf16* gWh1 = gWh0 + (size_t)64*K;
  const bf16* gWl0 = SPLIT ? Wl + (size_t)(bcol+sr)*K + sc : nullptr;
  const bf16* gWl1 = SPLIT ? gWl0 + (size_t)64*K : nullptr;
  const bf16* g2h0 = DUAL ? A2h + rg*M_ + sc : nullptr;
  const bf16* g2h1 = DUAL ? g2h0 + (size_t)64*M_ : nullptr;

  const int k0 = (MODE==MODE_VAL) ? (kz<<8) : 0;

  const int koff = ((lane>>4) ^ ((lane>>1)&3))*8;
  const int aoff = (wm*64 + (lane&15))*32 + koff;
  const int boff = (wn*64 + (lane&15))*32 + koff;

  bf16* const dA_0  = smem + wave*512;           bf16* const dA_1  = smem + BUFS + wave*512;
  bf16* const dW_0  = smem + 4096 + wave*512;    bf16* const dW_1  = smem + BUFS + 4096 + wave*512;
  bf16* const dAl_0 = SPLIT ? smem + 8192 + wave*512 : nullptr;
  bf16* const dAl_1 = SPLIT ? smem + BUFS + 8192 + wave*512 : nullptr;
  bf16* const dWl_0 = SPLIT ? smem + 12288 + wave*512 : nullptr;
  bf16* const dWl_1 = SPLIT ? smem + BUFS + 12288 + wave*512 : nullptr;
  const bf16* const Ash0 = smem;                 const bf16* const Ash1 = smem + BUFS;

  auto stage = [&](int kk, bf16* dA, bf16* dW, bf16* dAl, bf16* dWl){
    if constexpr (DUAL){
      if (kk < 1024){
        gload_lds16(gAh0 + kk, dA);
        gload_lds16(gAh1 + kk, dA + 2048);
      } else {
        gload_lds16(g2h0 + (kk-1024), dA);
        gload_lds16(g2h1 + (kk-1024), dA + 2048);
      }
    } else {
      gload_lds16(gAh0 + kk, dA);
      gload_lds16(gAh1 + kk, dA + 2048);
      if constexpr (SPLIT){
        gload_lds16(gAl0 + kk, dAl);
        gload_lds16(gAl1 + kk, dAl + 2048);
      }
    }
    gload_lds16(gWh0 + kk, dW);
    gload_lds16(gWh1 + kk, dW + 2048);
    if constexpr (SPLIT){
      gload_lds16(gWl0 + kk, dWl);
      gload_lds16(gWl1 + kk, dWl + 2048);
    }
  };
  auto compute = [&](const bf16* Ash){
    const bf16* Wsh = Ash + 4096;
    bfx8 ah[4], al[4], wh[4], wl[4];
    #pragma unroll
    for (int i=0;i<4;i++){
      ah[i] = *(const bfx8*)&Ash[aoff + i*512];
      wh[i] = *(const bfx8*)&Wsh[boff + i*512];
      if constexpr (SPLIT){
        al[i] = *(const bfx8*)&Ash[8192 + aoff + i*512];
        wl[i] = *(const bfx8*)&Ash[12288 + boff + i*512];
      }
    }
    __builtin_amdgcn_s_setprio(1);
    #pragma unroll
    for (int i=0;i<4;i++){
      #pragma unroll
      for (int j=0;j<4;j++){
        acc[i][j] = __builtin_amdgcn_mfma_f32_16x16x32_bf16(ah[i], wh[j], acc[i][j], 0,0,0);
        if constexpr (SPLIT){
          acc[i][j] = __builtin_amdgcn_mfma_f32_16x16x32_bf16(al[i], wh[j], acc[i][j], 0,0,0);
          acc[i][j] = __builtin_amdgcn_mfma_f32_16x16x32_bf16(ah[i], wl[j], acc[i][j], 0,0,0);
        }
      }
    }
    __builtin_amdgcn_s_setprio(0);
  };

  stage(k0,    dA_0, dW_0, dAl_0, dWl_0);
  stage(k0+32, dA_1, dW_1, dAl_1, dWl_1);
  if constexpr (SPLIT) PIPE_SYNC("8"); else PIPE_SYNC("4");
  compute(Ash0);
  PIPE_BAR();
  for (int it=1; it<=PAIRS; ++it){
    const int kk = k0 + it*64;
    stage(kk, dA_0, dW_0, dAl_0, dWl_0);
    if constexpr (SPLIT) PIPE_SYNC("8"); else PIPE_SYNC("4");
    compute(Ash1);
    PIPE_BAR();
    stage(kk+32, dA_1, dW_1, dAl_1, dWl_1);
    if constexpr (SPLIT) PIPE_SYNC("8"); else PIPE_SYNC("4");
    compute(Ash0);
    PIPE_BAR();
  }
  PIPE_SYNC("0");
  compute(Ash1);

  const int r0 = brow + wm*64 + (lane>>4)*4;
  const int c0 = bcol + wn*64 + (lane&15);
  #pragma unroll
  for (int j=0;j<4;j++){
    const int col = c0 + j*16;
    float bc = 0.f;
    if constexpr (MODE!=MODE_VAL) bc = bias[col];
    #pragma unroll
    for (int i=0;i<4;i++){
      #pragma unroll
      for (int r=0;r<4;r++){
        const size_t rr = (size_t)(r0 + i*16 + r);
        float v = acc[i][j][r] + bc;
        if constexpr (MODE==MODE_PW){
          v = siluf(v);
          const unsigned short h = f2bu(v);
          Cb1[rr*ldcb+col] = *(const bf16*)&h;
          const unsigned short lo = f2bu(v - us2f(h));
          Cb2[rr*ldcb+col] = *(const bf16*)&lo;
        } else if constexpr (MODE==MODE_VAL){
          atomicAdd(&Cf[rr*ldc+col], v);
        } else if constexpr (MODE==MODE_GATE){
          v += b2f(Ah[rr*(size_t)lda+col]) + b2f(Al[rr*(size_t)lda+col]);  // + h1 residual (hi+lo)
          Cf[rr*ldc+col] = v;
          Cb1[rr*ldcb+col] = __float2bfloat16(v);
        } else if constexpr (MODE==MODE_OUTW){
          Cf[rr*ldc+col] = v + resf[rr*ldres+col];
        } else if constexpr (MODE==MODE_DOWN){
          Cb1[rr*ldcb+col] = __float2bfloat16(geluf(v));
        } else if constexpr (MODE==MODE_UP){
          Cf[rr*ldc+col] = xin[rr*D_+col]*rs[0] + resf[rr*ldres+col] + v;
        }
      }
    }
  }
}

// ---------------- host launcher ----------------
extern "C" void kernel_launch(void* const* d_in, const int* in_sizes, int n_in,
                              void* d_out, int out_size, void* d_ws, size_t ws_size,
                              hipStream_t stream)
{
  (void)in_sizes; (void)n_in; (void)out_size; (void)ws_size;
  const float* x       = (const float*)d_in[0];
  const float* mem     = (const float*)d_in[1];
  const float* norm_w  = (const float*)d_in[2];
  const float* dw_w    = (const float*)d_in[3];
  const float* dw_b    = (const float*)d_in[4];
  const float* pw_w    = (const float*)d_in[5];
  const float* pw_b    = (const float*)d_in[6];
  const float* val_w   = (const float*)d_in[7];
  const float* val_b   = (const float*)d_in[8];
  const float* td      = (const float*)d_in[9];
  const float* tf      = (const float*)d_in[10];
  const float* gate_w  = (const float*)d_in[11];
  const float* gate_b  = (const float*)d_in[12];
  const float* rw      = (const float*)d_in[13];
  const float* rb      = (const float*)d_in[14];
  const float* exp_w   = (const float*)d_in[15];
  const float* exp_b   = (const float*)d_in[16];
  const float* out_w   = (const float*)d_in[17];
  const float* out_b   = (const float*)d_in[18];
  const float* fnorm_w = (const float*)d_in[19];
  const float* down_w  = (const float*)d_in[20];
  const float* down_b  = (const float*)d_in[21];
  const float* up_w    = (const float*)d_in[22];
  const float* up_b    = (const float*)d_in[23];
  const float* rs      = (const float*)d_in[24];

  char* ws = (char*)d_ws;
  const size_t MB = 1048576;
  bf16* pwh    = (bf16*)(ws + 0);
  bf16* pwl    = (bf16*)(ws + 2*MB);
  bf16* valh   = (bf16*)(ws + 4*MB);
  bf16* vall   = (bf16*)(ws + 4*MB + 524288);
  bf16* gatebf = (bf16*)(ws + 5*MB);
  bf16* expb   = (bf16*)(ws + 7*MB + 524288);
  bf16* outb   = (bf16*)(ws + 15*MB + 524288);
  bf16* downb  = (bf16*)(ws + 17*MB + 524288);
  bf16* upb    = (bf16*)(ws + 18*MB);
  float* gatesb= (float*)(ws + 18*MB + 524288);
  float* Rbuf  = (float*)(ws + 18*MB + 655360);
  float* c0buf = (float*)(ws + 18*MB + 655360 + 20480);
  float* carry = (float*)(ws + 18*MB + 786432);
  // meta zone
  char* MZ = ws + 18*MB + 917504;                 // 18.875MB
  int*   cntb  = (int*)(MZ);
  int*   cnt2b = (int*)(MZ + 64);
  unsigned int* midx = (unsigned int*)(MZ + 4096);
  float* mwb   = (float*)(MZ + 4096 + 69632);
  float* partb = (float*)(ws + 19*MB + 209715);   // ~19.2MB, 160KB partials
  // SlotA
  float* h0    = (float*)(ws + 20*MB);
  float* vbuf  = (float*)(ws + 20*MB);
  float* h2    = (float*)(ws + 20*MB);
  bf16*  h3bf  = (bf16 *)(ws + 20*MB);
  bf16*  dbf   = (bf16 *)(ws + 36*MB);
  // SlotB
  bf16*  yhi   = (bf16 *)(ws + 52*MB);
  bf16*  ylo   = (bf16 *)(ws + 68*MB);
  bf16*  h2bf  = (bf16 *)(ws + 52*MB);
  bf16*  wvhi  = (bf16 *)(ws + 68*MB);
  bf16*  wvlo  = (bf16 *)(ws + 72*MB);
  bf16*  S0    = (bf16 *)(ws + 68*MB);
  // SlotC
  bf16*  h1hi  = (bf16 *)(ws + 84*MB);
  bf16*  h1lo  = (bf16 *)(ws + 100*MB);
  bf16*  S1    = (bf16 *)(ws + 84*MB);
  bf16*  combbf= (bf16 *)(ws + 100*MB);

  float* out0 = (float*)d_out;
  float* nm   = (float*)d_out + (size_t)N_*D_;
  float* tbuf = (float*)d_out;
  float* h3   = (float*)d_out;

  const dim3 blk(256);
  k_prep1<<<1184, blk, 0, stream>>>(pw_w, val_w, gate_w, exp_w, out_w, down_w, up_w, rw,
                                    pwh, pwl, valh, vall, gatebf, expb, outb, downb, upb, partb);
  k_precomp2<<<21, blk, 0, stream>>>(partb, rw, gate_b, rb, Rbuf, c0buf);
  (void)hipMemsetAsync(MZ, 0, 256, stream);             // cnt + cnt2
  k_rms<false><<<N_, blk, 0, stream>>>(x, norm_w, h0, nullptr);
  k_conv<<<N_, blk, 0, stream>>>(h0, dw_w, dw_b, yhi, ylo);
  k_gemm<MODE_PW><<<512, blk, 0, stream>>>(yhi, ylo, D_, nullptr, pwh, pwl, D_,
      pw_b, nullptr, 0, h1hi, h1lo, D_, nullptr, 0, nullptr, nullptr);
  (void)hipMemsetAsync(vbuf, 0, (size_t)N_*M_*4, stream);
  k_gemm<MODE_VAL><<<512, blk, 0, stream>>>(h1hi, h1lo, D_, nullptr, valh, vall, D_,
      nullptr, vbuf, M_, nullptr, nullptr, 0, nullptr, 0, nullptr, nullptr);
  k_scan1<<<B_*CCH, blk, 0, stream>>>(vbuf, carry, td, val_b);
  k_scan3<<<B_*CCH, blk, 0, stream>>>(vbuf, carry, mem, td, tf, wvhi, wvlo, nm);
  k_gemm<MODE_GATE><<<512, blk, 0, stream>>>(h1hi, h1lo, D_, wvhi, gatebf, nullptr, 1280,
      gate_b, h2, D_, h2bf, nullptr, D_, nullptr, 0, nullptr, nullptr);
  k_rgemv<<<N_/4, blk, 0, stream>>>(h1hi, h1lo, wvhi, wvlo, Rbuf, c0buf, gatesb);
  // MoE bookkeeping + sparse experts
  k_count<<<N_/256, blk, 0, stream>>>(gatesb, cntb);
  k_assign<<<N_/256, blk, 0, stream>>>(gatesb, cntb, cnt2b, midx, mwb);
  k_expa<<<1056, blk, 0, stream>>>(h2bf, expb, exp_b, midx, mwb, cntb, S0, S1);
  k_combine<<<2048, blk, 0, stream>>>(S0, S1, combbf, N_*D_/4);
  k_gemm<MODE_OUTW><<<512, blk, 0, stream>>>(combbf, nullptr, D_, nullptr, outb, nullptr, D_,
      out_b, tbuf, D_, nullptr, nullptr, 0, h2, D_, nullptr, nullptr);
  k_rms<true><<<N_, blk, 0, stream>>>(tbuf, fnorm_w, h3, h3bf);
  k_gemm<MODE_DOWN><<<128, blk, 0, stream>>>(h3bf, nullptr, D_, nullptr, downb, nullptr, D_,
      down_b, nullptr, 0, dbf, nullptr, H_, nullptr, 0, nullptr, nullptr);
  k_gemm<MODE_UP><<<512, blk, 0, stream>>>(dbf, nullptr, H_, nullptr, upb, nullptr, H_,
      up_b, out0, D_, nullptr, nullptr, 0, h3, D_, x, rs);
}

// Round 17
// 482.134 us; speedup vs baseline: 1.0332x; 1.0332x over previous
//
#include <hip/hip_runtime.h>
#include <hip/hip_bf16.h>
#include <math.h>

using bf16 = __hip_bfloat16;
typedef __attribute__((ext_vector_type(8))) short bfx8;   // 8 x bf16 MFMA frag
typedef __attribute__((ext_vector_type(4))) float fx4;    // MFMA accum

#define DI __device__ __forceinline__

#define B_  4
#define L_  2048
#define D_  1024
#define M_  256
#define N_  8192            /* B*L tokens */
#define H_  256
#define CCH 32
#define TCH 64

// counted-vmcnt pipeline sync (T4): wait only for the OLDER stage's loads.
#define PIPE_SYNC(NSTR) asm volatile("s_waitcnt vmcnt(" NSTR ")\n\ts_barrier" ::: "memory")
#define PIPE_BAR()      asm volatile("s_barrier" ::: "memory")

DI float us2f(unsigned short u){ unsigned int i=((unsigned int)u)<<16; float f; __builtin_memcpy(&f,&i,4); return f; }
DI unsigned short f2bu(float f){ bf16 h=__float2bfloat16(f); unsigned short u; __builtin_memcpy(&u,&h,2); return u; }
DI float b2f(bf16 v){ return __bfloat162float(v); }
DI float siluf(float x){ return x/(1.f+expf(-x)); }
DI float geluf(float x){ return 0.5f*x*(1.f+erff(x*0.70710678118654752f)); }

DI void gload_lds16(const bf16* g, bf16* l){
  __builtin_amdgcn_global_load_lds((const __attribute__((address_space(1))) void*)g,
                                   (__attribute__((address_space(3))) void*)l, 16, 0, 0);
}

// ---- merged: weight prep (blocks 0..1023) + router-algebra stage1 (blocks 1024..1183) ----
__global__ __launch_bounds__(256) void k_prep1(const float* __restrict__ pw_w, const float* __restrict__ val_w,
    const float* __restrict__ gate_w, const float* __restrict__ exp_w, const float* __restrict__ out_w,
    const float* __restrict__ down_w, const float* __restrict__ up_w, const float* __restrict__ rw,
    bf16* pwh, bf16* pwl, bf16* valh, bf16* vall, bf16* gatebf, bf16* expb, bf16* outb, bf16* downb, bf16* upb,
    float* __restrict__ part)
{
  if (blockIdx.x < 1024){
    for (int i = blockIdx.x*256 + threadIdx.x; i < 2097152; i += 1024*256){
      const float* src; bf16* dsth; bf16* dstl = nullptr; int off;
      if (i < 262144)      { src=pw_w;   dsth=pwh;    dstl=pwl;  off=i; }
      else if (i < 327680) { src=val_w;  dsth=valh;   dstl=vall; off=i-262144; }
      else if (i < 655360) { src=gate_w; dsth=gatebf;            off=i-327680; }
      else if (i < 1703936){ src=exp_w;  dsth=expb;              off=i-655360; }
      else if (i < 1966080){ src=out_w;  dsth=outb;              off=i-1703936; }
      else if (i < 2031616){ src=down_w; dsth=downb;             off=i-1966080; }
      else                 { src=up_w;   dsth=upb;               off=i-2031616; }
      const float4 f = ((const float4*)src)[off];
      ushort4 h; h.x=f2bu(f.x); h.y=f2bu(f.y); h.z=f2bu(f.z); h.w=f2bu(f.w);
      ((ushort4*)dsth)[off] = h;
      if (dstl){
        ushort4 l;
        l.x=f2bu(f.x-us2f(h.x)); l.y=f2bu(f.y-us2f(h.y));
        l.z=f2bu(f.z-us2f(h.z)); l.w=f2bu(f.w-us2f(h.w));
        ((ushort4*)dstl)[off] = l;
      }
    }
  } else {
    const int bid = blockIdx.x - 1024;
    const int oc = bid/20, kb = bid - oc*20;
    const int ek = kb*256 + threadIdx.x;          // 0..5119
    const int e = ek/1280, k = ek - e*1280;
    const float* rwe = rw + e*1024 + oc*128;
    const float* g   = gate_w + (size_t)(oc*128)*1280 + k;
    float acc = 0.f;
    #pragma unroll 8
    for (int o=0;o<128;o++) acc = fmaf(rwe[o], g[(size_t)o*1280], acc);
    part[oc*5120 + ek] = acc;
  }
}

// ---- stage 2: R[e,k] = sum_oc part + rw[e,k] (k<1024); c0[e] = rw.gate_b + rb[e] ----
__global__ __launch_bounds__(256) void k_precomp2(const float* __restrict__ part, const float* __restrict__ rw,
                                                  const float* __restrict__ gb, const float* __restrict__ rb,
                                                  float* __restrict__ R, float* __restrict__ c0)
{
  const int ek = blockIdx.x*256 + threadIdx.x;
  if (ek < 5120){
    float s = 0.f;
    #pragma unroll
    for (int oc=0;oc<8;oc++) s += part[oc*5120 + ek];
    const int e = ek/1280, k = ek - e*1280;
    if (k < 1024) s += rw[e*1024 + k];
    R[ek] = s;
  } else if (ek < 5124){
    const int e = ek - 5120;
    float acc = rb[e];
    const float* rwe = rw + e*1024;
    #pragma unroll 8
    for (int o=0;o<1024;o++) acc = fmaf(rwe[o], gb[o], acc);
    c0[e] = acc;
  }
}

// ---------------- RMS norm (block = 1 token; in-place safe) ----------------
template<bool BF_OUT2>
__global__ __launch_bounds__(256) void k_rms(const float* inp, const float* __restrict__ w,
                                             float* outf, bf16* __restrict__ outbf)
{
  const int n = blockIdx.x, t = threadIdx.x;
  const float4 f = *((const float4*)inp + (size_t)n*(D_/4) + t);
  float s = f.x*f.x+f.y*f.y+f.z*f.z+f.w*f.w;
  #pragma unroll
  for (int off=32; off; off>>=1) s += __shfl_xor(s, off, 64);
  __shared__ float red[4];
  if ((t&63)==0) red[t>>6]=s;
  __syncthreads();
  const float inv = 1.f/sqrtf((red[0]+red[1]+red[2]+red[3])*(1.f/(float)D_)+1e-6f);
  const float4 wv = *((const float4*)w + t);
  float4 of;
  of.x = wv.x*f.x*inv; of.y = wv.y*f.y*inv; of.z = wv.z*f.z*inv; of.w = wv.w*f.w*inv;
  *((float4*)outf + (size_t)n*(D_/4) + t) = of;
  if constexpr (BF_OUT2){
    ushort4 ub; ub.x=f2bu(of.x); ub.y=f2bu(of.y); ub.z=f2bu(of.z); ub.w=f2bu(of.w);
    *((ushort4*)outbf + (size_t)n*(D_/4) + t) = ub;
  }
}

// ---------------- causal depthwise conv K=5; out split hi/lo ----------------
__global__ __launch_bounds__(256) void k_conv(const float* __restrict__ h0, const float* __restrict__ dww,
                                              const float* __restrict__ dwb,
                                              bf16* __restrict__ yhi, bf16* __restrict__ ylo)
{
  const int n = blockIdx.x, t = threadIdx.x;
  const int l = n & (L_-1);
  const int d0 = t*4;
  float a0=dwb[d0+0], a1=dwb[d0+1], a2=dwb[d0+2], a3=dwb[d0+3];
  #pragma unroll
  for (int k=0;k<5;k++){
    if (l-4+k < 0) continue;
    const float4 h4 = *(const float4*)&h0[(size_t)(n+k-4)*D_ + d0];
    a0 += h4.x*dww[(d0+0)*5+k];
    a1 += h4.y*dww[(d0+1)*5+k];
    a2 += h4.z*dww[(d0+2)*5+k];
    a3 += h4.w*dww[(d0+3)*5+k];
  }
  ushort4 hi, lo;
  hi.x=f2bu(a0); lo.x=f2bu(a0-us2f(hi.x));
  hi.y=f2bu(a1); lo.y=f2bu(a1-us2f(hi.y));
  hi.z=f2bu(a2); lo.z=f2bu(a2-us2f(hi.z));
  hi.w=f2bu(a3); lo.w=f2bu(a3-us2f(hi.w));
  *((ushort4*)yhi + (size_t)n*(D_/4) + t) = hi;
  *((ushort4*)ylo + (size_t)n*(D_/4) + t) = lo;
}

// ---------------- chunked scan (in-place over v; adds val bias) ----------------
__global__ __launch_bounds__(256) void k_scan1(float* vw, float* __restrict__ carry,
                                               const float* __restrict__ td, const float* __restrict__ vb)
{
  const int bc = blockIdx.x, m = threadIdx.x;
  const int b = bc>>5, c = bc&(CCH-1);
  const float decay = 0.9f/(1.f+expf(-td[m])) + 0.1f;
  const float bias = vb[m];
  float* wp = vw + ((size_t)b*L_ + c*TCH)*M_ + m;
  float a = 0.f;
  for (int i=0;i<TCH;i++){ a = a*decay + (wp[(size_t)i*M_] + bias); wp[(size_t)i*M_] = a; }
  carry[(size_t)bc*M_ + m] = a;
}

// scan3 with inline carry-prefix (replaces scan2): cin = Horner over raw chunk-ends, same fp order
__global__ __launch_bounds__(256) void k_scan3(const float* __restrict__ wv, const float* __restrict__ carry,
                                               const float* __restrict__ mem, const float* __restrict__ td,
                                               const float* __restrict__ tf,
                                               bf16* __restrict__ wvhi, bf16* __restrict__ wvlo,
                                               float* __restrict__ nextmem)
{
  const int bc = blockIdx.x, m = threadIdx.x;
  const int b = bc>>5, c = bc&(CCH-1);
  const float decay = 0.9f/(1.f+expf(-td[m])) + 0.1f;
  const float dT = powf(decay, (float)TCH);
  float cin = 0.f;
  for (int j=0;j<c;j++) cin = carry[((size_t)(b*CCH+j))*M_ + m] + dT*cin;
  const float memc = mem[b*M_+m] / (1.f+expf(-tf[m]));
  const float* wp = wv + ((size_t)b*L_ + c*TCH)*M_ + m;
  float p = 1.f;
  for (int i=0;i<TCH;i++){
    p *= decay;
    const float val = wp[(size_t)i*M_] + p*cin + memc;
    const int l = c*TCH+i;
    const size_t n = (size_t)b*L_ + l;
    const unsigned short h = f2bu(val);
    wvhi[n*M_ + m] = *(const bf16*)&h;
    const unsigned short lo = f2bu(val - us2f(h));
    wvlo[n*M_ + m] = *(const bf16*)&lo;
    if (l == L_-1) nextmem[b*M_+m] = val;
  }
}

// ---------------- precise router: logits = h1.R1^T + wv.R2^T + c0 ; top-2 softmax -> gates ----------------
__global__ __launch_bounds__(256) void k_rgemv(const bf16* __restrict__ h1hi, const bf16* __restrict__ h1lo,
                                               const bf16* __restrict__ wvhi, const bf16* __restrict__ wvlo,
                                               const float* __restrict__ R, const float* __restrict__ c0,
                                               float* __restrict__ gates)
{
  const int wave = threadIdx.x>>6, lane = threadIdx.x&63;
  const size_t n = (size_t)blockIdx.x*4 + wave;
  float p0=0,p1=0,p2=0,p3=0;
  const ushort4* hhi = (const ushort4*)(h1hi + n*D_);
  const ushort4* hlo = (const ushort4*)(h1lo + n*D_);
  #pragma unroll
  for (int c=0;c<4;c++){
    const int k4 = c*64 + lane;
    const ushort4 uh = hhi[k4], ul = hlo[k4];
    const float v0=us2f(uh.x)+us2f(ul.x), v1=us2f(uh.y)+us2f(ul.y);
    const float v2=us2f(uh.z)+us2f(ul.z), v3=us2f(uh.w)+us2f(ul.w);
    const float4 r0 = *(const float4*)&R[0*1280 + k4*4];
    const float4 r1 = *(const float4*)&R[1*1280 + k4*4];
    const float4 r2 = *(const float4*)&R[2*1280 + k4*4];
    const float4 r3 = *(const float4*)&R[3*1280 + k4*4];
    p0 += v0*r0.x+v1*r0.y+v2*r0.z+v3*r0.w;
    p1 += v0*r1.x+v1*r1.y+v2*r1.z+v3*r1.w;
    p2 += v0*r2.x+v1*r2.y+v2*r2.z+v3*r2.w;
    p3 += v0*r3.x+v1*r3.y+v2*r3.z+v3*r3.w;
  }
  {
    const ushort4 uh = ((const ushort4*)(wvhi + n*M_))[lane];
    const ushort4 ul = ((const ushort4*)(wvlo + n*M_))[lane];
    const float v0=us2f(uh.x)+us2f(ul.x), v1=us2f(uh.y)+us2f(ul.y);
    const float v2=us2f(uh.z)+us2f(ul.z), v3=us2f(uh.w)+us2f(ul.w);
    const float4 r0 = *(const float4*)&R[0*1280 + 1024 + lane*4];
    const float4 r1 = *(const float4*)&R[1*1280 + 1024 + lane*4];
    const float4 r2 = *(const float4*)&R[2*1280 + 1024 + lane*4];
    const float4 r3 = *(const float4*)&R[3*1280 + 1024 + lane*4];
    p0 += v0*r0.x+v1*r0.y+v2*r0.z+v3*r0.w;
    p1 += v0*r1.x+v1*r1.y+v2*r1.z+v3*r1.w;
    p2 += v0*r2.x+v1*r2.y+v2*r2.z+v3*r2.w;
    p3 += v0*r3.x+v1*r3.y+v2*r3.z+v3*r3.w;
  }
  #pragma unroll
  for (int off=32; off; off>>=1){
    p0 += __shfl_xor(p0, off, 64); p1 += __shfl_xor(p1, off, 64);
    p2 += __shfl_xor(p2, off, 64); p3 += __shfl_xor(p3, off, 64);
  }
  if (lane==0){
    float lg[4] = {p0+c0[0], p1+c0[1], p2+c0[2], p3+c0[3]};
    int i1=0; float m1=lg[0];
    #pragma unroll
    for (int e=1;e<4;e++) if (lg[e]>m1){ m1=lg[e]; i1=e; }
    int i2=-1; float m2=-1e30f;
    #pragma unroll
    for (int e=0;e<4;e++) if (e!=i1 && lg[e]>m2){ m2=lg[e]; i2=e; }
    const float ex = expf(m2-m1);
    const float w1 = 1.f/(1.f+ex), w2 = ex/(1.f+ex);
    float4 g; g.x=0; g.y=0; g.z=0; g.w=0;
    ((float*)&g)[i1]=w1; ((float*)&g)[i2]=w2;
    *(float4*)&gates[n*4] = g;
  }
}

// ---------------- MoE bookkeeping ----------------
__global__ __launch_bounds__(256) void k_count(const float* __restrict__ gates, int* __restrict__ cnt)
{
  const int n = blockIdx.x*256 + threadIdx.x;
  const float4 g = *(const float4*)&gates[(size_t)n*4];
  if (g.x>0.f) atomicAdd(&cnt[0],1);
  if (g.y>0.f) atomicAdd(&cnt[1],1);
  if (g.z>0.f) atomicAdd(&cnt[2],1);
  if (g.w>0.f) atomicAdd(&cnt[3],1);
}

DI void base_from_cnt(const int* cnt, int* basearr){
  int s = 0;
  #pragma unroll
  for (int e=0;e<4;e++){ basearr[e]=s; s += ((cnt[e]+127)>>7)<<7; }
  basearr[4] = s;
}

// wave-aggregated position assignment; base computed inline from cnt
__global__ __launch_bounds__(256) void k_assign(const float* __restrict__ gates, const int* __restrict__ cnt,
                                                int* __restrict__ cnt2, unsigned int* __restrict__ midx,
                                                float* __restrict__ mw)
{
  int cl[4] = {cnt[0],cnt[1],cnt[2],cnt[3]};
  int basearr[5]; base_from_cnt(cl, basearr);
  const int n = blockIdx.x*256 + threadIdx.x;
  const int lane = threadIdx.x & 63;
  const float4 g = *(const float4*)&gates[(size_t)n*4];
  const float ga[4] = {g.x,g.y,g.z,g.w};
  int ea=-1, ebx=-1; float wa=0.f, wb=0.f;
  #pragma unroll
  for (int e=0;e<4;e++){
    const float ge = ga[e];
    if (ge>0.f){ if (ea<0){ea=e;wa=ge;} else {ebx=e;wb=ge;} }
  }
  int s0e, s1e=-1; float s0w, s1w=0.f;
  if (ebx<0){ s0e=ea; s0w=wa; }
  else if (wa>=wb){ s0e=ea; s0w=wa; s1e=ebx; s1w=wb; }
  else            { s0e=ebx; s0w=wb; s1e=ea; s1w=wa; }

  #pragma unroll
  for (int e=0;e<4;e++){
    #pragma unroll
    for (int slot=0;slot<2;slot++){
      const bool want = (slot==0) ? (s0e==e) : (s1e==e);
      const unsigned long long mask = __ballot(want);
      if (mask == 0ull) continue;
      const int leader = __ffsll((long long)mask) - 1;
      int pos = 0;
      if (lane == leader) pos = atomicAdd(&cnt2[e], __popcll(mask));
      pos = __shfl(pos, leader, 64);
      if (want){
        const int rank = __popcll(mask & ((1ull<<lane)-1ull));
        const int idx = basearr[e] + pos + rank;
        midx[idx] = (unsigned)n | (slot ? 0x80000000u : 0u);
        mw[idx]   = slot ? s1w : s0w;
      }
    }
  }
}

// ---------------- sparse expert GEMM: static dbuf, depth-2 counted-vmcnt pipeline, setprio ----------------
__global__ __launch_bounds__(256) void k_expa(const bf16* __restrict__ A, const bf16* __restrict__ Wall,
                                              const float* __restrict__ eb,
                                              const unsigned int* __restrict__ midx, const float* __restrict__ mw,
                                              const int* __restrict__ cnt,
                                              bf16* __restrict__ S0, bf16* __restrict__ S1)
{
  __shared__ __align__(16) bf16 smem[2*8192];

  int cl[4] = {cnt[0],cnt[1],cnt[2],cnt[3]};
  int basearr[5]; base_from_cnt(cl, basearr);
  const int nrb = basearr[4]>>7;

  const int bid = blockIdx.x;
  const int id2 = (bid&7)*132 + (bid>>3);          // XCD swizzle
  const int rblk = id2>>3, bcol0 = (id2&7)<<7;
  if (rblk >= nrb) return;
  const int row0 = rblk<<7;
  int e=0;
  if (row0 >= basearr[1]) e=1;
  if (row0 >= basearr[2]) e=2;
  if (row0 >= basearr[3]) e=3;
  const int loc0 = row0 - basearr[e];
  const int cnte = cl[e];

  const int t = threadIdx.x, wave = t>>6, lane = t&63;
  const int wm = wave>>1, wn = wave&1;
  fx4 acc[4][4] = {};

  const int sr = t>>2;
  const int sc = ((t&3) ^ ((t>>3)&3))*8;
  const unsigned mr0 = midx[row0+sr], mr1 = midx[row0+64+sr];
  const int tok0 = min((int)(mr0 & 0x7FFFFFFFu), N_-1);
  const int tok1 = min((int)(mr1 & 0x7FFFFFFFu), N_-1);
  const bf16* gA0 = A + (size_t)tok0*D_ + sc;
  const bf16* gA1 = A + (size_t)tok1*D_ + sc;
  const bf16* gW0 = Wall + (size_t)e*D_*D_ + (size_t)(bcol0+sr)*D_ + sc;
  const bf16* gW1 = gW0 + (size_t)64*D_;

  const int koff = ((lane>>4) ^ ((lane>>1)&3))*8;
  const int aoff = (wm*64 + (lane&15))*32 + koff;
  const int boff = (wn*64 + (lane&15))*32 + koff;

  bf16* const dA_0 = smem + wave*512;          bf16* const dW_0 = smem + 4096 + wave*512;
  bf16* const dA_1 = smem + 8192 + wave*512;   bf16* const dW_1 = smem + 8192 + 4096 + wave*512;
  const bf16* const Ash0 = smem;               const bf16* const Ash1 = smem + 8192;

  auto stage = [&](int kk, bf16* dA, bf16* dW){
    gload_lds16(gA0 + kk, dA);
    gload_lds16(gA1 + kk, dA + 2048);
    gload_lds16(gW0 + kk, dW);
    gload_lds16(gW1 + kk, dW + 2048);
  };
  auto compute = [&](const bf16* Ash){
    const bf16* Wsh = Ash + 4096;
    bfx8 ah[4], wh[4];
    #pragma unroll
    for (int i=0;i<4;i++){
      ah[i] = *(const bfx8*)&Ash[aoff + i*512];
      wh[i] = *(const bfx8*)&Wsh[boff + i*512];
    }
    __builtin_amdgcn_s_setprio(1);
    #pragma unroll
    for (int i=0;i<4;i++)
      #pragma unroll
      for (int j=0;j<4;j++)
        acc[i][j] = __builtin_amdgcn_mfma_f32_16x16x32_bf16(ah[i], wh[j], acc[i][j], 0,0,0);
    __builtin_amdgcn_s_setprio(0);
  };

  stage(0, dA_0, dW_0);
  stage(32, dA_1, dW_1);
  PIPE_SYNC("4");
  compute(Ash0);
  PIPE_BAR();
  for (int it=1; it<=15; ++it){
    const int kk = it*64;
    stage(kk, dA_0, dW_0);
    PIPE_SYNC("4");
    compute(Ash1);
    PIPE_BAR();
    stage(kk+32, dA_1, dW_1);
    PIPE_SYNC("4");
    compute(Ash0);
    PIPE_BAR();
  }
  PIPE_SYNC("0");
  compute(Ash1);

  const int r0l = wm*64 + (lane>>4)*4;
  const int c0l = wn*64 + (lane&15);
  #pragma unroll
  for (int i=0;i<4;i++){
    #pragma unroll
    for (int r=0;r<4;r++){
      const int loc = loc0 + r0l + i*16 + r;
      if (loc >= cnte) continue;
      const int gr = row0 + r0l + i*16 + r;
      const unsigned mi = midx[gr];
      const int tok = (int)(mi & 0x7FFFFFFFu);
      const float w = mw[gr];
      bf16* Sd = (mi & 0x80000000u) ? S1 : S0;
      #pragma unroll
      for (int j=0;j<4;j++){
        const int col = bcol0 + c0l + j*16;
        const float v = acc[i][j][r] + eb[(e<<10)+col];
        Sd[(size_t)tok*D_ + col] = __float2bfloat16(w*siluf(v));
      }
    }
  }
}

// ---------------- combine: combbf = bf16(S0 + S1) ----------------
__global__ __launch_bounds__(256) void k_combine(const bf16* __restrict__ S0, const bf16* __restrict__ S1,
                                                 bf16* __restrict__ o, int n4)
{
  int i = blockIdx.x*256 + threadIdx.x;
  const int stride = gridDim.x*256;
  for (; i<n4; i+=stride){
    const ushort4 a = ((const ushort4*)S0)[i];
    const ushort4 b = ((const ushort4*)S1)[i];
    ushort4 c;
    c.x = f2bu(us2f(a.x)+us2f(b.x));
    c.y = f2bu(us2f(a.y)+us2f(b.y));
    c.z = f2bu(us2f(a.z)+us2f(b.z));
    c.w = f2bu(us2f(a.w)+us2f(b.w));
    ((ushort4*)o)[i] = c;
  }
}

// ---------------- MFMA GEMM (static dbuf, depth-2 counted-vmcnt pipeline) ----------------
enum GMode { MODE_PW=0, MODE_VAL, MODE_GATE, MODE_OUTW, MODE_DOWN, MODE_UP };

template<int MODE>
__global__ __launch_bounds__(256)
void k_gemm(const bf16* __restrict__ Ah, const bf16* __restrict__ Al, const int lda,
            const bf16* __restrict__ A2h,
            const bf16* __restrict__ Wh, const bf16* __restrict__ Wl, const int K,
            const float* __restrict__ bias,
            float* Cf, const int ldc,
            bf16* __restrict__ Cb1, bf16* __restrict__ Cb2, const int ldcb,
            const float* resf, const int ldres,
            const float* __restrict__ xin, const float* __restrict__ rs)
{
  constexpr bool SPLIT = (MODE==MODE_PW || MODE==MODE_VAL);   // 3-pass hi/lo precision
  constexpr bool DUAL  = (MODE==MODE_GATE);                   // K>1024 from wv segment
  constexpr int  BUFS  = SPLIT ? 16384 : 8192;
  constexpr int  KSTEPS = (MODE==MODE_VAL || MODE==MODE_UP) ? 8 : (MODE==MODE_GATE ? 40 : 32);
  constexpr int  PAIRS  = (KSTEPS-2)/2;
  __shared__ __align__(16) bf16 smem[2*BUFS];

  const int t = threadIdx.x, wave = t>>6, lane = t&63;
  const int bid = blockIdx.x;
  int brow, bcol, kz = 0;
  if constexpr (MODE==MODE_VAL){
    const int id2 = (bid&7)*64 + (bid>>3);
    const int ct = id2 & 7;
    bcol = (ct&1)<<7; kz = ct>>1; brow = (id2>>3)<<7;
  } else if constexpr (MODE==MODE_DOWN){
    const int id2 = (bid&7)*16 + (bid>>3);
    bcol = (id2&1)<<7; brow = (id2>>1)<<7;
  } else {
    const int id2 = (bid&7)*64 + (bid>>3);
    bcol = (id2&7)<<7; brow = (id2>>3)<<7;
  }
  const int wm = wave>>1, wn = wave&1;
  fx4 acc[4][4] = {};

  const int sr = t>>2;
  const int sc = ((t&3) ^ ((t>>3)&3))*8;
  const size_t rg = (size_t)(brow+sr);
  const bf16* gAh0 = Ah + rg*lda + sc;
  const bf16* gAh1 = gAh0 + (size_t)64*lda;
  const bf16* gAl0 = SPLIT ? Al + rg*lda + sc : nullptr;
  const bf16* gAl1 = SPLIT ? gAl0 + (size_t)64*lda : nullptr;
  const bf16* gWh0 = Wh + (size_t)(bcol+sr)*K + sc;
  const bf16* gWh1 = gWh0 + (size_t)64*K;
  const bf16* gWl0 = SPLIT ? Wl + (size_t)(bcol+sr)*K + sc : nullptr;
  const bf16* gWl1 = SPLIT ? gWl0 + (size_t)64*K : nullptr;
  const bf16* g2h0 = DUAL ? A2h + rg*M_ + sc : nullptr;
  const bf16* g2h1 = DUAL ? g2h0 + (size_t)64*M_ : nullptr;

  const int k0 = (MODE==MODE_VAL) ? (kz<<8) : 0;

  const int koff = ((lane>>4) ^ ((lane>>1)&3))*8;
  const int aoff = (wm*64 + (lane&15))*32 + koff;
  const int boff = (wn*64 + (lane&15))*32 + koff;

  bf16* const dA_0  = smem + wave*512;           bf16* const dA_1  = smem + BUFS + wave*512;
  bf16* const dW_0  = smem + 4096 + wave*512;    bf16* const dW_1  = smem + BUFS + 4096 + wave*512;
  bf16* const dAl_0 = SPLIT ? smem + 8192 + wave*512 : nullptr;
  bf16* const dAl_1 = SPLIT ? smem + BUFS + 8192 + wave*512 : nullptr;
  bf16* const dWl_0 = SPLIT ? smem + 12288 + wave*512 : nullptr;
  bf16* const dWl_1 = SPLIT ? smem + BUFS + 12288 + wave*512 : nullptr;
  const bf16* const Ash0 = smem;                 const bf16* const Ash1 = smem + BUFS;

  auto stage = [&](int kk, bf16* dA, bf16* dW, bf16* dAl, bf16* dWl){
    if constexpr (DUAL){
      if (kk < 1024){
        gload_lds16(gAh0 + kk, dA);
        gload_lds16(gAh1 + kk, dA + 2048);
      } else {
        gload_lds16(g2h0 + (kk-1024), dA);
        gload_lds16(g2h1 + (kk-1024), dA + 2048);
      }
    } else {
      gload_lds16(gAh0 + kk, dA);
      gload_lds16(gAh1 + kk, dA + 2048);
      if constexpr (SPLIT){
        gload_lds16(gAl0 + kk, dAl);
        gload_lds16(gAl1 + kk, dAl + 2048);
      }
    }
    gload_lds16(gWh0 + kk, dW);
    gload_lds16(gWh1 + kk, dW + 2048);
    if constexpr (SPLIT){
      gload_lds16(gWl0 + kk, dWl);
      gload_lds16(gWl1 + kk, dWl + 2048);
    }
  };
  auto compute = [&](const bf16* Ash){
    const bf16* Wsh = Ash + 4096;
    bfx8 ah[4], al[4], wh[4], wl[4];
    #pragma unroll
    for (int i=0;i<4;i++){
      ah[i] = *(const bfx8*)&Ash[aoff + i*512];
      wh[i] = *(const bfx8*)&Wsh[boff + i*512];
      if constexpr (SPLIT){
        al[i] = *(const bfx8*)&Ash[8192 + aoff + i*512];
        wl[i] = *(const bfx8*)&Ash[12288 + boff + i*512];
      }
    }
    __builtin_amdgcn_s_setprio(1);
    #pragma unroll
    for (int i=0;i<4;i++){
      #pragma unroll
      for (int j=0;j<4;j++){
        acc[i][j] = __builtin_amdgcn_mfma_f32_16x16x32_bf16(ah[i], wh[j], acc[i][j], 0,0,0);
        if constexpr (SPLIT){
          acc[i][j] = __builtin_amdgcn_mfma_f32_16x16x32_bf16(al[i], wh[j], acc[i][j], 0,0,0);
          acc[i][j] = __builtin_amdgcn_mfma_f32_16x16x32_bf16(ah[i], wl[j], acc[i][j], 0,0,0);
        }
      }
    }
    __builtin_amdgcn_s_setprio(0);
  };

  stage(k0,    dA_0, dW_0, dAl_0, dWl_0);
  stage(k0+32, dA_1, dW_1, dAl_1, dWl_1);
  if constexpr (SPLIT) PIPE_SYNC("8"); else PIPE_SYNC("4");
  compute(Ash0);
  PIPE_BAR();
  for (int it=1; it<=PAIRS; ++it){
    const int kk = k0 + it*64;
    stage(kk, dA_0, dW_0, dAl_0, dWl_0);
    if constexpr (SPLIT) PIPE_SYNC("8"); else PIPE_SYNC("4");
    compute(Ash1);
    PIPE_BAR();
    stage(kk+32, dA_1, dW_1, dAl_1, dWl_1);
    if constexpr (SPLIT) PIPE_SYNC("8"); else PIPE_SYNC("4");
    compute(Ash0);
    PIPE_BAR();
  }
  PIPE_SYNC("0");
  compute(Ash1);

  const int r0 = brow + wm*64 + (lane>>4)*4;
  const int c0 = bcol + wn*64 + (lane&15);
  #pragma unroll
  for (int j=0;j<4;j++){
    const int col = c0 + j*16;
    float bc = 0.f;
    if constexpr (MODE!=MODE_VAL) bc = bias[col];
    #pragma unroll
    for (int i=0;i<4;i++){
      #pragma unroll
      for (int r=0;r<4;r++){
        const size_t rr = (size_t)(r0 + i*16 + r);
        float v = acc[i][j][r] + bc;
        if constexpr (MODE==MODE_PW){
          v = siluf(v);
          const unsigned short h = f2bu(v);
          Cb1[rr*ldcb+col] = *(const bf16*)&h;
          const unsigned short lo = f2bu(v - us2f(h));
          Cb2[rr*ldcb+col] = *(const bf16*)&lo;
        } else if constexpr (MODE==MODE_VAL){
          atomicAdd(&Cf[rr*ldc+col], v);
        } else if constexpr (MODE==MODE_GATE){
          v += b2f(Ah[rr*(size_t)lda+col]) + b2f(Al[rr*(size_t)lda+col]);  // + h1 residual (hi+lo)
          Cf[rr*ldc+col] = v;
          Cb1[rr*ldcb+col] = __float2bfloat16(v);
        } else if constexpr (MODE==MODE_OUTW){
          Cf[rr*ldc+col] = v + resf[rr*ldres+col];
        } else if constexpr (MODE==MODE_DOWN){
          Cb1[rr*ldcb+col] = __float2bfloat16(geluf(v));
        } else if constexpr (MODE==MODE_UP){
          Cf[rr*ldc+col] = xin[rr*D_+col]*rs[0] + resf[rr*ldres+col] + v;
        }
      }
    }
  }
}

// ---------------- host launcher ----------------
extern "C" void kernel_launch(void* const* d_in, const int* in_sizes, int n_in,
                              void* d_out, int out_size, void* d_ws, size_t ws_size,
                              hipStream_t stream)
{
  (void)in_sizes; (void)n_in; (void)out_size; (void)ws_size;
  const float* x       = (const float*)d_in[0];
  const float* mem     = (const float*)d_in[1];
  const float* norm_w  = (const float*)d_in[2];
  const float* dw_w    = (const float*)d_in[3];
  const float* dw_b    = (const float*)d_in[4];
  const float* pw_w    = (const float*)d_in[5];
  const float* pw_b    = (const float*)d_in[6];
  const float* val_w   = (const float*)d_in[7];
  const float* val_b   = (const float*)d_in[8];
  const float* td      = (const float*)d_in[9];
  const float* tf      = (const float*)d_in[10];
  const float* gate_w  = (const float*)d_in[11];
  const float* gate_b  = (const float*)d_in[12];
  const float* rw      = (const float*)d_in[13];
  const float* rb      = (const float*)d_in[14];
  const float* exp_w   = (const float*)d_in[15];
  const float* exp_b   = (const float*)d_in[16];
  const float* out_w   = (const float*)d_in[17];
  const float* out_b   = (const float*)d_in[18];
  const float* fnorm_w = (const float*)d_in[19];
  const float* down_w  = (const float*)d_in[20];
  const float* down_b  = (const float*)d_in[21];
  const float* up_w    = (const float*)d_in[22];
  const float* up_b    = (const float*)d_in[23];
  const float* rs      = (const float*)d_in[24];

  char* ws = (char*)d_ws;
  const size_t MB = 1048576;
  bf16* pwh    = (bf16*)(ws + 0);
  bf16* pwl    = (bf16*)(ws + 2*MB);
  bf16* valh   = (bf16*)(ws + 4*MB);
  bf16* vall   = (bf16*)(ws + 4*MB + 524288);
  bf16* gatebf = (bf16*)(ws + 5*MB);
  bf16* expb   = (bf16*)(ws + 7*MB + 524288);
  bf16* outb   = (bf16*)(ws + 15*MB + 524288);
  bf16* downb  = (bf16*)(ws + 17*MB + 524288);
  bf16* upb    = (bf16*)(ws + 18*MB);
  float* gatesb= (float*)(ws + 18*MB + 524288);
  float* Rbuf  = (float*)(ws + 18*MB + 655360);
  float* c0buf = (float*)(ws + 18*MB + 655360 + 20480);
  float* carry = (float*)(ws + 18*MB + 786432);
  // meta zone
  char* MZ = ws + 18*MB + 917504;                 // 18.875MB
  int*   cntb  = (int*)(MZ);
  int*   cnt2b = (int*)(MZ + 64);
  unsigned int* midx = (unsigned int*)(MZ + 4096);
  float* mwb   = (float*)(MZ + 4096 + 69632);
  float* partb = (float*)(ws + 19*MB + 209715);   // ~19.2MB, 160KB partials
  // SlotA
  float* h0    = (float*)(ws + 20*MB);
  float* vbuf  = (float*)(ws + 20*MB);
  float* h2    = (float*)(ws + 20*MB);
  bf16*  h3bf  = (bf16 *)(ws + 20*MB);
  bf16*  dbf   = (bf16 *)(ws + 36*MB);
  // SlotB
  bf16*  yhi   = (bf16 *)(ws + 52*MB);
  bf16*  ylo   = (bf16 *)(ws + 68*MB);
  bf16*  h2bf  = (bf16 *)(ws + 52*MB);
  bf16*  wvhi  = (bf16 *)(ws + 68*MB);
  bf16*  wvlo  = (bf16 *)(ws + 72*MB);
  bf16*  S0    = (bf16 *)(ws + 68*MB);
  // SlotC
  bf16*  h1hi  = (bf16 *)(ws + 84*MB);
  bf16*  h1lo  = (bf16 *)(ws + 100*MB);
  bf16*  S1    = (bf16 *)(ws + 84*MB);
  bf16*  combbf= (bf16 *)(ws + 100*MB);

  float* out0 = (float*)d_out;
  float* nm   = (float*)d_out + (size_t)N_*D_;
  float* tbuf = (float*)d_out;
  float* h3   = (float*)d_out;

  const dim3 blk(256);
  k_prep1<<<1184, blk, 0, stream>>>(pw_w, val_w, gate_w, exp_w, out_w, down_w, up_w, rw,
                                    pwh, pwl, valh, vall, gatebf, expb, outb, downb, upb, partb);
  k_precomp2<<<21, blk, 0, stream>>>(partb, rw, gate_b, rb, Rbuf, c0buf);
  (void)hipMemsetAsync(MZ, 0, 256, stream);             // cnt + cnt2
  k_rms<false><<<N_, blk, 0, stream>>>(x, norm_w, h0, nullptr);
  k_conv<<<N_, blk, 0, stream>>>(h0, dw_w, dw_b, yhi, ylo);
  k_gemm<MODE_PW><<<512, blk, 0, stream>>>(yhi, ylo, D_, nullptr, pwh, pwl, D_,
      pw_b, nullptr, 0, h1hi, h1lo, D_, nullptr, 0, nullptr, nullptr);
  (void)hipMemsetAsync(vbuf, 0, (size_t)N_*M_*4, stream);
  k_gemm<MODE_VAL><<<512, blk, 0, stream>>>(h1hi, h1lo, D_, nullptr, valh, vall, D_,
      nullptr, vbuf, M_, nullptr, nullptr, 0, nullptr, 0, nullptr, nullptr);
  k_scan1<<<B_*CCH, blk, 0, stream>>>(vbuf, carry, td, val_b);
  k_scan3<<<B_*CCH, blk, 0, stream>>>(vbuf, carry, mem, td, tf, wvhi, wvlo, nm);
  k_gemm<MODE_GATE><<<512, blk, 0, stream>>>(h1hi, h1lo, D_, wvhi, gatebf, nullptr, 1280,
      gate_b, h2, D_, h2bf, nullptr, D_, nullptr, 0, nullptr, nullptr);
  k_rgemv<<<N_/4, blk, 0, stream>>>(h1hi, h1lo, wvhi, wvlo, Rbuf, c0buf, gatesb);
  // MoE bookkeeping + sparse experts
  k_count<<<N_/256, blk, 0, stream>>>(gatesb, cntb);
  k_assign<<<N_/256, blk, 0, stream>>>(gatesb, cntb, cnt2b, midx, mwb);
  k_expa<<<1056, blk, 0, stream>>>(h2bf, expb, exp_b, midx, mwb, cntb, S0, S1);
  k_combine<<<2048, blk, 0, stream>>>(S0, S1, combbf, N_*D_/4);
  k_gemm<MODE_OUTW><<<512, blk, 0, stream>>>(combbf, nullptr, D_, nullptr, outb, nullptr, D_,
      out_b, tbuf, D_, nullptr, nullptr, 0, h2, D_, nullptr, nullptr);
  k_rms<true><<<N_, blk, 0, stream>>>(tbuf, fnorm_w, h3, h3bf);
  k_gemm<MODE_DOWN><<<128, blk, 0, stream>>>(h3bf, nullptr, D_, nullptr, downb, nullptr, D_,
      down_b, nullptr, 0, dbf, nullptr, H_, nullptr, 0, nullptr, nullptr);
  k_gemm<MODE_UP><<<512, blk, 0, stream>>>(dbf, nullptr, H_, nullptr, upb, nullptr, H_,
      up_b, out0, D_, nullptr, nullptr, 0, h3, D_, x, rs);
}